// Round 3
// baseline (70.550 us; speedup 1.0000x reference)
//
#include <hip/hip_runtime.h>

// MaxMinComp: out[b,o] = max_i min(x[b,i], W[i,o]); B=1024, IN=OUT=512, fp32.
// fp16-packed tropical GEMM (threshold 2e-2; cvt err ~5e-4). All values in
// [0,1) => halves nonneg => IEEE order == unsigned order => packed u16 min/max.
//
// R1: 8 waves/CU -> ~31us. R2: 16 waves/CU -> ~27us (occupancy barely helped;
// not latency-bound). R3 theory: __builtin_elementwise_min(u16x2) scalarized
// (~6 VALU/op instead of 1 v_pk_min_u16) -> VALU-bound at ~20us. Fix: inline
// asm v_pk_min_u16 / v_pk_max_u16 (guaranteed single VOP3P). Everything else
// identical to R2 for clean A/B.

typedef unsigned int u32;
typedef u32 u32x2 __attribute__((ext_vector_type(2)));
typedef u32 u32x4 __attribute__((ext_vector_type(4)));
typedef float f4 __attribute__((ext_vector_type(4)));
typedef float f2 __attribute__((ext_vector_type(2)));
typedef __fp16 h2 __attribute__((ext_vector_type(2)));

#define IN_F 512
#define OUT_F 512
#define XS_BYTES 8192                    // [k=64][row=32] * 4B broadcast pair
#define WS_BYTES 8192                    // [k=64][col=64] * 2B
#define BUF_BYTES (XS_BYTES + WS_BYTES)  // 16384

static __device__ __forceinline__ u32 pkcvt(float a, float b) {
  return __builtin_bit_cast(u32, __builtin_amdgcn_cvt_pkrtz(a, b));
}
static __device__ __forceinline__ u32 pkmin(u32 a, u32 b) {
  u32 d;
  asm("v_pk_min_u16 %0, %1, %2" : "=v"(d) : "v"(a), "v"(b));
  return d;
}
static __device__ __forceinline__ u32 pkmax(u32 a, u32 b) {
  u32 d;
  asm("v_pk_max_u16 %0, %1, %2" : "=v"(d) : "v"(a), "v"(b));
  return d;
}

__global__ __launch_bounds__(1024, 4) void maxmin_v3(const float* __restrict__ X,
                                                     const float* __restrict__ W,
                                                     float* __restrict__ Out) {
  __shared__ __align__(16) char smem[65536];  // 2x16KB staging; 64KB epilogue overlay

  const int tid  = threadIdx.x;
  const int wv   = tid >> 6;   // wave 0..15 -> k range [4*wv, 4*wv+4) per chunk
  const int lane = tid & 63;
  const int ty   = lane >> 3;  // rows 4*ty .. 4*ty+3
  const int tx   = lane & 7;   // cols 8*tx .. 8*tx+7
  const int b0   = blockIdx.x * 32;
  const int o0   = blockIdx.y * 64;

  // x staging (threads with xq<16): row = tid&31 spreads LDS transpose-writes
  // across banks (2 lanes/bank = free per m136).
  const int xrow = tid & 31;
  const int xq   = tid >> 5;  // k-quad 0..31; only <16 participates
  const bool dox = (xq < 16);
  const float* xg = X + (b0 + xrow) * IN_F + xq * 4;

  // w staging (all 1024 threads, one float4 each): coalesced.
  const int wrow = tid >> 4;  // 0..63
  const int wc4  = tid & 15;
  const float* wg = W + wrow * OUT_F + o0 + wc4 * 4;

  // compute-side LDS byte offsets (k_local = wv*4 + j)
  const int xs_r = (wv * 4) * 128 + ty * 16;
  const int ws_r = XS_BYTES + (wv * 4) * 128 + tx * 16;

  // staging-write LDS byte offsets
  const int xw = xrow * 4;                        // + (4*xq+e)*128
  const int ww = XS_BYTES + wrow * 128 + wc4 * 8;

  u32 acc[4][4] = {};  // +0.0h packed; valid identity (all values >= 0)

  auto stage = [&](char* buf, f4 xv, f4 wv4) {
    u32x2 wp = {pkcvt(wv4.x, wv4.y), pkcvt(wv4.z, wv4.w)};
    *(u32x2*)(buf + ww) = wp;
    if (dox) {
      *(u32*)(buf + (4 * xq + 0) * 128 + xw) = pkcvt(xv.x, xv.x);
      *(u32*)(buf + (4 * xq + 1) * 128 + xw) = pkcvt(xv.y, xv.y);
      *(u32*)(buf + (4 * xq + 2) * 128 + xw) = pkcvt(xv.z, xv.z);
      *(u32*)(buf + (4 * xq + 3) * 128 + xw) = pkcvt(xv.w, xv.w);
    }
  };

  // prologue: stage chunk 0
  f4 xv = {};
  if (dox) xv = *(const f4*)xg;
  f4 wv4 = *(const f4*)wg;
  stage(smem, xv, wv4);
  __syncthreads();

  for (int c = 0; c < 8; ++c) {
    f4 nx = {}, nw = {};
    if (c < 7) {  // next chunk's global loads issued before compute
      if (dox) nx = *(const f4*)(xg + (c + 1) * 64);
      nw = *(const f4*)(wg + (c + 1) * 64 * OUT_F);
    }
    const char* buf = smem + (c & 1) * BUF_BYTES;
#pragma unroll
    for (int j = 0; j < 4; ++j) {
      u32x4 xqv = *(const u32x4*)(buf + xs_r + j * 128);
      u32x4 wqv = *(const u32x4*)(buf + ws_r + j * 128);
#pragma unroll
      for (int i = 0; i < 4; ++i)
#pragma unroll
        for (int jj = 0; jj < 4; ++jj)
          acc[i][jj] = pkmax(acc[i][jj], pkmin(xqv[i], wqv[jj]));
    }
    if (c < 7) stage(smem + ((c + 1) & 1) * BUF_BYTES, nx, nw);
    __syncthreads();
  }

  // epilogue: 16 per-wave partials -> LDS overlay [wv][row 0..31][colpair 0..31]
#pragma unroll
  for (int i = 0; i < 4; ++i) {
    u32x4 v = {acc[i][0], acc[i][1], acc[i][2], acc[i][3]};
    *(u32x4*)(smem + wv * 4096 + (4 * ty + i) * 128 + tx * 16) = v;
  }
  __syncthreads();

  const int row = tid >> 5;  // 0..31
  const int cp  = tid & 31;  // col-pair 0..31
  const int cb  = row * 128 + cp * 4;
  u32 m = *(const u32*)(smem + cb);
#pragma unroll
  for (int g = 1; g < 16; ++g) m = pkmax(m, *(const u32*)(smem + g * 4096 + cb));
  h2 hm = __builtin_bit_cast(h2, m);
  f2 o = {(float)hm.x, (float)hm.y};
  *(f2*)(Out + (b0 + row) * OUT_F + o0 + cp * 2) = o;
}

extern "C" void kernel_launch(void* const* d_in, const int* in_sizes, int n_in,
                              void* d_out, int out_size, void* d_ws, size_t ws_size,
                              hipStream_t stream) {
  const float* x = (const float*)d_in[0];
  const float* w = (const float*)d_in[1];
  float* out = (float*)d_out;
  (void)in_sizes; (void)n_in; (void)out_size; (void)d_ws; (void)ws_size;
  dim3 grid(1024 / 32, 512 / 64);  // 32 x 8 = 256 blocks, 1024 thr = 16 waves
  maxmin_v3<<<grid, 1024, 0, stream>>>(x, w, out);
}